// Round 1
// 447.406 us; speedup vs baseline: 1.0258x; 1.0258x over previous
//
#include <hip/hip_runtime.h>

#define S_STEPS 1024
#define BATCH 128
#define NQ 8
#define XW_FLOATS (BATCH * 32 * 1024)    // 16.78 MB in d_ws

using v2f     = float __attribute__((ext_vector_type(2)));
using frag_ab = __attribute__((ext_vector_type(8))) short;   // 8 bf16
using frag_cd = __attribute__((ext_vector_type(4))) float;   // 4 fp32

#define INV2PI 0.15915494309189535f

// ---- helpers -----------------------------------------------------------
template<int CTRL>
__device__ __forceinline__ float dppf(float x) {   // quad_perm splat (order-free)
  return __int_as_float(__builtin_amdgcn_update_dpp(0, __float_as_int(x), CTRL, 0xf, 0xf, true));
}
__device__ __forceinline__ float bperm(int addr, float v) {
  return __int_as_float(__builtin_amdgcn_ds_bpermute(addr, __float_as_int(v)));
}
__device__ __forceinline__ short f2bf(float f) {   // fp32 -> bf16 (RNE)
  unsigned u = __float_as_uint(f);
  return (short)((u + 0x7FFFu + ((u >> 16) & 1u)) >> 16);
}
__device__ __forceinline__ float bf2f(short h) {
  return __uint_as_float(((unsigned)(unsigned short)h) << 16);
}

// ---- kernel 1: MFMA GEMM.  xw[(b*32+c)*1024+t] = (bias_c + x[t,b,:]·Wc)/2π
// Restructured t-major for occupancy + coalesced stores:
//   wave tile = 16t x 32c x 1b; 8192 waves (8/SIMD target) vs old 1024 (1/SIMD).
//   A = W (c rows, staged in LDS as bf16 hi/lo, pitch 264 shorts -> balanced banks)
//   B = x (t cols)  => D col (lane&15) = t  => 64B-contiguous dword stores.
//   Same 3-mfma hi/lo split as before (Whi*xhi + Wlo*xhi + Whi*xlo).
__global__ __launch_bounds__(512) void qlstm_pre(
    const float* __restrict__ x,
    const float* __restrict__ Wf, const float* __restrict__ bf_,
    const float* __restrict__ Wi, const float* __restrict__ bi,
    const float* __restrict__ Wu, const float* __restrict__ bu,
    const float* __restrict__ Wo, const float* __restrict__ bo,
    float* __restrict__ xw)
{
  __shared__ short whi[32 * 264];   // 16896 B
  __shared__ short wlo[32 * 264];   // 16896 B

  const int tid = threadIdx.x;

  // ---- stage W (scaled by 1/2π, split bf16 hi/lo) into LDS: 16 elems/thread
  {
    const int base = tid * 16;              // 512*16 = 8192 = 32c * 256k
    const int c = base >> 8, k0 = base & 255;
    const int g = c >> 3, w = c & 7;
    const float* Wg = (g == 0) ? Wf : (g == 1) ? Wi : (g == 2) ? Wu : Wo;
    const float* p = Wg + w * 264 + k0;
    const int o = c * 264 + k0;
#pragma unroll
    for (int q = 0; q < 2; ++q) {
      float4 va = *(const float4*)(p + q * 8);
      float4 vb = *(const float4*)(p + q * 8 + 4);
      float vv[8] = {va.x, va.y, va.z, va.w, vb.x, vb.y, vb.z, vb.w};
      frag_ab h8, l8;
#pragma unroll
      for (int j = 0; j < 8; ++j) {
        float wv = vv[j] * INV2PI;
        short h = f2bf(wv);
        h8[j] = h;
        l8[j] = f2bf(wv - bf2f(h));
      }
      *(frag_ab*)&whi[o + q * 8] = h8;
      *(frag_ab*)&wlo[o + q * 8] = l8;
    }
  }
  __syncthreads();

  const int lane = tid & 63;
  const int m  = lane & 15;                 // t offset (B-frag col) / W row (A-frag)
  const int kg = lane >> 4;                 // k group
  const int gid = blockIdx.x * 8 + (tid >> 6);   // 0..8191
  const int b  = gid >> 6;                  // 0..127
  const int t0 = (gid & 63) << 4;           // 0..1008

  // bias for the 8 c-values this lane will store: c = n*16 + kg*4 + r
  float bb[2][4];
#pragma unroll
  for (int n = 0; n < 2; ++n)
#pragma unroll
    for (int r = 0; r < 4; ++r) {
      int c = n * 16 + kg * 4 + r;
      int g = c >> 3, w = c & 7;
      const float* bg = (g == 0) ? bf_ : (g == 1) ? bi : (g == 2) ? bu : bo;
      bb[n][r] = bg[w] * INV2PI;
    }

  const float* xbase = x + ((size_t)(t0 + m) * 128 + b) * 256 + kg * 8;
  const int w0 = m * 264 + kg * 8;          // LDS row for n=0 (c = m)
  const int w1 = w0 + 16 * 264;             // n=1 (c = 16+m)

  frag_cd acc0 = {0.f, 0.f, 0.f, 0.f};
  frag_cd acc1 = {0.f, 0.f, 0.f, 0.f};

  float4 xv0 = *(const float4*)(xbase);
  float4 xv1 = *(const float4*)(xbase + 4);

#pragma unroll 1
  for (int kk = 0; kk < 8; ++kk) {
    // prefetch next k-chunk (uniform branch; last iter keeps current regs)
    float4 nx0 = xv0, nx1 = xv1;
    if (kk < 7) {
      nx0 = *(const float4*)(xbase + (kk + 1) * 32);
      nx1 = *(const float4*)(xbase + (kk + 1) * 32 + 4);
    }
    frag_ab a0h = *(const frag_ab*)&whi[w0 + kk * 32];
    frag_ab a0l = *(const frag_ab*)&wlo[w0 + kk * 32];
    frag_ab a1h = *(const frag_ab*)&whi[w1 + kk * 32];
    frag_ab a1l = *(const frag_ab*)&wlo[w1 + kk * 32];

    float xf[8] = {xv0.x, xv0.y, xv0.z, xv0.w, xv1.x, xv1.y, xv1.z, xv1.w};
    frag_ab xh, xl;
#pragma unroll
    for (int j = 0; j < 8; ++j) {
      short h = f2bf(xf[j]);
      xh[j] = h;
      xl[j] = f2bf(xf[j] - bf2f(h));
    }

    acc0 = __builtin_amdgcn_mfma_f32_16x16x32_bf16(a0h, xh, acc0, 0, 0, 0);
    acc0 = __builtin_amdgcn_mfma_f32_16x16x32_bf16(a0l, xh, acc0, 0, 0, 0);
    acc0 = __builtin_amdgcn_mfma_f32_16x16x32_bf16(a0h, xl, acc0, 0, 0, 0);
    acc1 = __builtin_amdgcn_mfma_f32_16x16x32_bf16(a1h, xh, acc1, 0, 0, 0);
    acc1 = __builtin_amdgcn_mfma_f32_16x16x32_bf16(a1l, xh, acc1, 0, 0, 0);
    acc1 = __builtin_amdgcn_mfma_f32_16x16x32_bf16(a1h, xl, acc1, 0, 0, 0);

    xv0 = nx0; xv1 = nx1;
  }

  // D: col = lane&15 = t offset; row = kg*4 + r = c within n-tile.
  // Store: 16 consecutive lanes -> 64 contiguous bytes (coalesced).
#pragma unroll
  for (int n = 0; n < 2; ++n) {
    const frag_cd a = n ? acc1 : acc0;
#pragma unroll
    for (int r = 0; r < 4; ++r)
      xw[((size_t)(b * 32 + n * 16 + kg * 4 + r)) * 1024 + t0 + m] = a[r] + bb[n][r];
  }
}

// ---- kernel 2: recurrence. 32 blocks x 64 thr; 4 batches/wave, 16 lanes/batch.
// (unchanged this round)
__global__ __launch_bounds__(64) void qlstm_seq(
    const float* __restrict__ xw,
    const float* __restrict__ Wf, const float* __restrict__ Wi,
    const float* __restrict__ Wu, const float* __restrict__ Wo,
    float* __restrict__ out)
{
  const int lane = threadIdx.x;
  const int r = lane & 15, g = r >> 2, k = r & 3;
  const int b = blockIdx.x * 4 + (lane >> 4);
  const int B6 = (k >> 1) & 1, B7 = k & 1;
  const bool isB7 = (B7 != 0);
  const float s6 = B6 ? -1.f : 1.f,        o6 = B6 ? 1.f : 0.f;
  const float s7 = (B7^B6) ? -1.f : 1.f,   o7 = (B7^B6) ? 1.f : 0.f;
  const int wA = (k == 0) ? 0 : (k == 1) ? 5 : 7;
  const int wB = (k == 0) ? 1 : (k == 1) ? 6 : 7;

  const float* Wg = (g == 0) ? Wf : (g == 1) ? Wi : (g == 2) ? Wu : Wo;
  v2f whA2[4], whB2[4];
#pragma unroll
  for (int j2 = 0; j2 < 4; ++j2) {
    whA2[j2] = (v2f){Wg[wA*264+256+2*j2] * INV2PI, Wg[wA*264+256+2*j2+1] * INV2PI};
    whB2[j2] = (v2f){Wg[wB*264+256+2*j2] * INV2PI, Wg[wB*264+256+2*j2+1] * INV2PI};
  }

  // bpermute source addresses (bytes): lane (b^,g',k) for g'=0..3
  const int aF = (((lane & 48) | k) << 2);
  const int aI = aF + 16, aU = aF + 32, aO = aF + 48;

  v2f h2[4];
#pragma unroll
  for (int j = 0; j < 4; ++j) h2[j] = (v2f){0.f, 0.f};
  float cA = 0.f, cB = 0.f, hqA = 0.f, hqB = 0.f;

  const float* bxw = xw + (size_t)b * 32768;
  const float4* pA = (const float4*)(bxw + (size_t)(g * 8 + wA) * 1024);
  const float4* pB = (const float4*)(bxw + (size_t)(g * 8 + wB) * 1024);
  float4 curA = pA[0], nxtA = pA[1];
  float4 curB = pB[0], nxtB = pB[1];

  const int soff = b * 8 + r;     // valid for r<8 (= g*4+k)
  float houtS[16];

#pragma unroll 1
  for (int Tb = 0; Tb < S_STEPS; Tb += 16) {
#pragma unroll
    for (int sg = 0; sg < 4; ++sg) {
      int gi = (Tb >> 2) + sg;
      int tp = gi + 2; tp = (tp > 255) ? 255 : tp;
      float4 nnA = pA[tp], nnB = pB[tp];
#pragma unroll
      for (int u = 0; u < 4; ++u) {
        float xa = (u==0)?curA.x:(u==1)?curA.y:(u==2)?curA.z:curA.w;
        float xb = (u==0)?curB.x:(u==1)?curB.y:(u==2)?curB.z:curB.w;
        v2f accA = whA2[0]*h2[0]; accA = whA2[1]*h2[1] + accA;
        accA = whA2[2]*h2[2] + accA; accA = whA2[3]*h2[3] + accA;
        v2f accB = whB2[0]*h2[0]; accB = whB2[1]*h2[1] + accB;
        accB = whB2[2]*h2[2] + accB; accB = whB2[3]*h2[3] + accB;
        float pa = (xa + accA.x) + accA.y;     // revolutions
        float pb = (xb + accB.x) + accB.y;
        float ccA = fmaf(0.5f, __builtin_amdgcn_cosf(pa), 0.5f);
        float ccB = fmaf(0.5f, __builtin_amdgcn_cosf(pb), 0.5f);

        // phase A: quad splats (wire cos^2, shared within gate)
        float C0 = dppf<0x00>(ccA), C1 = dppf<0x00>(ccB);
        float C5 = dppf<0x55>(ccA), C6 = dppf<0x55>(ccB);
        float C7 = dppf<0xAA>(ccA);

        // numerators + shared denominator
        float S0v = 1.f - C0, S1v = 1.f - C1;
        float P01 = C0 * C1, Q01 = S0v * S1v;
        float sel01 = isB7 ? Q01 : P01;        // = F0*F1
        float F7  = fmaf(s7, C7, o7);
        float F6A = fmaf(s6, C6, o6);
        float e7  = sel01 * F7;
        float dA  = C5 * F6A;
        float dB  = (1.f + dA) - (C5 + F6A);   // (1-C5)(1-F6A)
        float d56 = C5 * C6;
        float U0  = fmaf(2.f, d56, 1.f - (C5 + C6));
        float S7v = 1.f - C7;
        float T0  = fmaf(fmaf(2.f, C7, -1.f), U0, S7v);
        float sden = fmaf(P01 - Q01, T0, Q01);
        float es  = e7 * __builtin_amdgcn_rcpf(sden);
        float pnA = es * dA, pnB = es * dB;

        // phase C: cross-gate all-gather via bpermute
        float fvA = bperm(aF, pnA), ivA = bperm(aI, pnA);
        float uvA = bperm(aU, pnA), ovA = bperm(aO, pnA);
        float fvB = bperm(aF, pnB), ivB = bperm(aI, pnB);
        float uvB = bperm(aU, pnB), ovB = bperm(aO, pnB);

        // LSTM, index k (A) and k+4 (B)
        float t2A = uvA * uvA;
        float gvA = uvA * (t2A + 15.f) * __builtin_amdgcn_rcpf(fmaf(6.f, t2A, 15.f));
        cA = fmaf(fvA, cA, ivA * gvA);
        float eA = __builtin_amdgcn_exp2f(fminf(cA, 15.f) * 2.88539008f);
        hqA = ovA * fmaf(-2.f, __builtin_amdgcn_rcpf(eA + 1.f), 1.f);
        float t2B = uvB * uvB;
        float gvB = uvB * (t2B + 15.f) * __builtin_amdgcn_rcpf(fmaf(6.f, t2B, 15.f));
        cB = fmaf(fvB, cB, ivB * gvB);
        float eB = __builtin_amdgcn_exp2f(fminf(cB, 15.f) * 2.88539008f);
        hqB = ovB * fmaf(-2.f, __builtin_amdgcn_rcpf(eB + 1.f), 1.f);

        // phase D: quad splats -> h pairs (h0..h7)
        h2[0].x = dppf<0x00>(hqA); h2[0].y = dppf<0x55>(hqA);
        h2[1].x = dppf<0xAA>(hqA); h2[1].y = dppf<0xFF>(hqA);
        h2[2].x = dppf<0x00>(hqB); h2[2].y = dppf<0x55>(hqB);
        h2[3].x = dppf<0xAA>(hqB); h2[3].y = dppf<0xFF>(hqB);

        houtS[sg * 4 + u] = (g == 0) ? hqA : hqB;
      }
      curA = nxtA; nxtA = nnA;
      curB = nxtB; nxtB = nnB;
    }
    if (r < 8) {
      float* op = out + (size_t)Tb * (BATCH * NQ) + soff;
#pragma unroll
      for (int tt = 0; tt < 16; ++tt)
        op[(size_t)tt * (BATCH * NQ)] = houtS[tt];
    }
  }
  if (r < 8) {
    size_t o1 = (size_t)S_STEPS * BATCH * NQ + soff;
    out[o1] = (g == 0) ? hqA : hqB;                       // h_n
    out[o1 + (size_t)BATCH * NQ] = (g == 0) ? cA : cB;    // c_n
  }
}

extern "C" void kernel_launch(void* const* d_in, const int* in_sizes, int n_in,
                              void* d_out, int out_size, void* d_ws, size_t ws_size,
                              hipStream_t stream) {
  const float* x  = (const float*)d_in[0];
  const float* Wf = (const float*)d_in[1];
  const float* bf = (const float*)d_in[2];
  const float* Wi = (const float*)d_in[3];
  const float* bi = (const float*)d_in[4];
  const float* Wu = (const float*)d_in[5];
  const float* bu = (const float*)d_in[6];
  const float* Wo = (const float*)d_in[7];
  const float* bo = (const float*)d_in[8];
  float* xw  = (float*)d_ws;               // (128*32, 1024) floats = 16.78 MB
  float* out = (float*)d_out;

  qlstm_pre<<<1024, 512, 0, stream>>>(x, Wf, bf, Wi, bi, Wu, bu, Wo, bo, xw);
  qlstm_seq<<<32, 64, 0, stream>>>(xw, Wf, Wi, Wu, Wo, out);
}